// Round 6
// baseline (435.138 us; speedup 1.0000x reference)
//
#include <hip/hip_runtime.h>

#define DEVINL __device__ __forceinline__

DEVINL float leaky(float v) { return v >= 0.f ? v : 0.2f * v; }

// ---------------------------------------------------------------------------
// Precompute per-level head projection vectors (unchanged).
// ---------------------------------------------------------------------------
__global__ void wprep_kernel(const float* __restrict__ lin,   // (6,64,64)
                             const float* __restrict__ asrc,  // (6,4,16)
                             const float* __restrict__ adst,  // (6,4,16)
                             float* __restrict__ w_out) {     // (6,2,4,64)
    int idx = blockIdx.x * blockDim.x + threadIdx.x;
    if (idx >= 6 * 4 * 64) return;
    int c = idx & 63;
    int h = (idx >> 6) & 3;
    int k = idx >> 8;
    const float* L = lin + k * 64 * 64;
    float s1 = 0.f, s2 = 0.f;
    for (int e = 0; e < 16; ++e) {
        float w = L[(h * 16 + e) * 64 + c];
        s1 += w * asrc[(k * 4 + h) * 16 + e];
        s2 += w * adst[(k * 4 + h) * 16 + e];
    }
    w_out[(k * 2 + 0) * 256 + h * 64 + c] = s1;
    w_out[(k * 2 + 1) * 256 + h * 64 + c] = s2;
}

// ---------------------------------------------------------------------------
// Transpose pool weights once (unchanged).
// ---------------------------------------------------------------------------
__global__ void wtrans_kernel(const float* __restrict__ s0, const float* __restrict__ s1,
                              const float* __restrict__ t0, const float* __restrict__ t1,
                              const float* __restrict__ s0w2, const float* __restrict__ s1w2,
                              const float* __restrict__ t0w2, const float* __restrict__ t1w2,
                              float* __restrict__ o) {
    int idx = blockIdx.x * 256 + threadIdx.x;
    if (idx < 16384) {
        int m = idx >> 12, r = idx & 4095, c = r >> 6, d = r & 63;
        const float* src = (m == 0) ? s0 : (m == 1) ? s1 : (m == 2) ? t0 : t1;
        o[idx] = src[d * 64 + c];
    } else if (idx < 16384 + 768) {
        int j = idx - 16384, c = j / 12, k = j - 12 * c;
        o[idx] = s0w2[k * 64 + c];
    } else if (idx < 17152 + 512) {
        int j = idx - 17152, c = j >> 3, k = j & 7;
        o[idx] = (k < 5) ? s1w2[k * 64 + c] : 0.f;
    } else if (idx < 17664 + 2048) {
        int j = idx - 17664, c = j >> 5, k = j & 31;
        o[idx] = t0w2[k * 64 + c];
    } else if (idx < 19712 + 768) {
        int j = idx - 19712, c = j / 12, k = j - 12 * c;
        o[idx] = t1w2[k * 64 + c];
    }
}

// ---------------------------------------------------------------------------
// Diff-pool + fused transpose-staging + fused score emission.
// MODE 0: x is (G,N,64). MODE 1: x = src, spatial graph g=(b*64+t).
// MODE 2: x = src, temporal graph g=(b*25+j).
// Emits sci = scores of input x (MODE!=0), sco = scores of output xo.
// WR: write xo to global.
// ---------------------------------------------------------------------------
template <int N, int K, int KP, int MODE, int WR>
__global__ __launch_bounds__(256) void pool_kernel(
    const float* __restrict__ x, const float* __restrict__ W1T,
    const float* __restrict__ b1, const float* __restrict__ W2T,
    const float* __restrict__ b2, const float* __restrict__ wsi,
    const float* __restrict__ wso, float* __restrict__ xo,
    float* __restrict__ sci, float* __restrict__ sco)
{
    constexpr int SLD = KP + 1;
    constexpr int XO_OFF = ((N * SLD + 3) & ~3);
    constexpr int SZT = (MODE == 1) ? 64 * 26 : (MODE == 2 ? 64 * 65 : 0);
    constexpr int R3A = XO_OFF + K * 68;
    constexpr int R3 = ((R3A > SZT ? R3A : SZT) + 3) & ~3;
    constexpr int TOT = 2 * N * 68 + R3 + 512;
    __shared__ float lds[TOT];
    float* xln = lds;                 // [N][68]
    float* yn  = lds + N * 68;        // [N][68]
    float* r3  = yn + N * 68;
    float* sn  = r3;                  // [N][SLD]
    float* xoL = r3 + XO_OFF;         // [K][68]
    float* wlo = r3 + R3;             // 512
    float* wli = yn;                  // alias: used only before GEMM1 writes yn
    float* tile = r3;                 // alias: staging only
    const int g = blockIdx.x, tid = threadIdx.x;

    // ---- stage input
    if constexpr (MODE == 0) {
        const float4* xp = (const float4*)(x + (size_t)g * N * 64);
        for (int p = tid; p < N * 16; p += 256) {
            int n = p >> 4, c0 = (p & 15) << 2;
            *(float4*)&xln[n * 68 + c0] = xp[p];
        }
    } else if constexpr (MODE == 1) {
        int b = g >> 6, t = g & 63;
        const float* sp = x + b * 102400 + t * 25;
        for (int idx = tid; idx < 1600; idx += 256) {
            int c = idx / 25, j = idx - c * 25;
            tile[c * 26 + j] = sp[c * 1600 + j];
        }
        for (int i = tid; i < 512; i += 256) wli[i] = wsi[i];
    } else {
        int b = g / 25, j = g - b * 25;
        const float* sp = x + b * 102400 + j;
        for (int idx = tid; idx < 4096; idx += 256) {
            int c = idx >> 6, t = idx & 63;
            tile[c * 65 + t] = sp[c * 1600 + t * 25];
        }
        for (int i = tid; i < 512; i += 256) wli[i] = wsi[i];
    }
    for (int i = tid; i < 512; i += 256) wlo[i] = wso[i];
    __syncthreads();

    if constexpr (MODE != 0) {
        constexpr int TLD = (MODE == 1) ? 26 : 65;
        for (int p = tid; p < N * 64; p += 256) {
            int n = p >> 6, c = p & 63;
            xln[n * 68 + c] = tile[c * TLD + n];
        }
        __syncthreads();
        // scores of the input x
        for (int p = tid; p < 8 * N; p += 256) {
            int q = p / N, n = p - q * N;
            const float* wv = wli + q * 64;
            const float* xr = &xln[n * 68];
            float acc = 0.f;
            #pragma unroll
            for (int c0 = 0; c0 < 64; c0 += 4) {
                float4 xv = *(const float4*)&xr[c0];
                float4 w4 = *(const float4*)&wv[c0];
                acc += xv.x * w4.x + xv.y * w4.y + xv.z * w4.z + xv.w * w4.w;
            }
            sci[(size_t)g * 8 * N + p] = acc;
        }
        __syncthreads();   // wli (=yn) must be fully read before GEMM1 writes yn
    }

    // ---- GEMM1: y = relu(x @ W1^T + b1)
    for (int p = tid; p < N * 16; p += 256) {
        int n = p >> 4, d0 = (p & 15) << 2;
        const float* xr = &xln[n * 68];
        float4 bb = *(const float4*)(b1 + d0);
        float a0 = bb.x, a1 = bb.y, a2 = bb.z, a3 = bb.w;
        #pragma unroll 4
        for (int c0 = 0; c0 < 64; c0 += 4) {
            float4 xv = *(const float4*)&xr[c0];
            float4 w0 = *(const float4*)(W1T + (c0 + 0) * 64 + d0);
            float4 w1 = *(const float4*)(W1T + (c0 + 1) * 64 + d0);
            float4 w2 = *(const float4*)(W1T + (c0 + 2) * 64 + d0);
            float4 w3 = *(const float4*)(W1T + (c0 + 3) * 64 + d0);
            a0 += xv.x * w0.x + xv.y * w1.x + xv.z * w2.x + xv.w * w3.x;
            a1 += xv.x * w0.y + xv.y * w1.y + xv.z * w2.y + xv.w * w3.y;
            a2 += xv.x * w0.z + xv.y * w1.z + xv.z * w2.z + xv.w * w3.z;
            a3 += xv.x * w0.w + xv.y * w1.w + xv.z * w2.w + xv.w * w3.w;
        }
        *(float4*)&yn[n * 68 + d0] =
            make_float4(fmaxf(a0, 0.f), fmaxf(a1, 0.f), fmaxf(a2, 0.f), fmaxf(a3, 0.f));
    }
    __syncthreads();

    // ---- GEMM2: s = y @ W2^T + b2 (pad k -> -1e30)
    for (int p = tid; p < N * (KP / 4); p += 256) {
        int n = p / (KP / 4), k0 = (p % (KP / 4)) << 2;
        const float* yr = &yn[n * 68];
        float a0 = 0.f, a1 = 0.f, a2 = 0.f, a3 = 0.f;
        #pragma unroll 4
        for (int d0 = 0; d0 < 64; d0 += 4) {
            float4 yv = *(const float4*)&yr[d0];
            float4 w0 = *(const float4*)(W2T + (d0 + 0) * KP + k0);
            float4 w1 = *(const float4*)(W2T + (d0 + 1) * KP + k0);
            float4 w2 = *(const float4*)(W2T + (d0 + 2) * KP + k0);
            float4 w3 = *(const float4*)(W2T + (d0 + 3) * KP + k0);
            a0 += yv.x * w0.x + yv.y * w1.x + yv.z * w2.x + yv.w * w3.x;
            a1 += yv.x * w0.y + yv.y * w1.y + yv.z * w2.y + yv.w * w3.y;
            a2 += yv.x * w0.z + yv.y * w1.z + yv.z * w2.z + yv.w * w3.z;
            a3 += yv.x * w0.w + yv.y * w1.w + yv.z * w2.w + yv.w * w3.w;
        }
        float* sr = &sn[n * SLD + k0];
        sr[0] = (k0 + 0 < K) ? a0 + b2[k0 + 0] : -1e30f;
        sr[1] = (k0 + 1 < K) ? a1 + b2[k0 + 1] : -1e30f;
        sr[2] = (k0 + 2 < K) ? a2 + b2[k0 + 2] : -1e30f;
        sr[3] = (k0 + 3 < K) ? a3 + b2[k0 + 3] : -1e30f;
    }
    __syncthreads();

    // ---- softmax over k per row
    if (tid < N) {
        float* sr = &sn[tid * SLD];
        float m = sr[0];
        #pragma unroll
        for (int k = 1; k < KP; ++k) m = fmaxf(m, sr[k]);
        float sum = 0.f;
        #pragma unroll
        for (int k = 0; k < KP; ++k) { float e = __expf(sr[k] - m); sr[k] = e; sum += e; }
        float inv = 1.f / sum;
        #pragma unroll
        for (int k = 0; k < KP; ++k) sr[k] *= inv;
    }
    __syncthreads();

    // ---- GEMM3: xo[k][c] = sum_n s[n][k] * x[n][c]
    for (int p = tid; p < K * 16; p += 256) {
        int k = p >> 4, c0 = (p & 15) << 2;
        float a0 = 0.f, a1 = 0.f, a2 = 0.f, a3 = 0.f;
        for (int n = 0; n < N; ++n) {
            float s = sn[n * SLD + k];
            float4 xv = *(const float4*)&xln[n * 68 + c0];
            a0 += s * xv.x; a1 += s * xv.y; a2 += s * xv.z; a3 += s * xv.w;
        }
        float4 r = make_float4(a0, a1, a2, a3);
        *(float4*)&xoL[k * 68 + c0] = r;
        if constexpr (WR)
            *(float4*)(xo + (size_t)g * K * 64 + k * 64 + c0) = r;
    }
    __syncthreads();

    // ---- scores of output xo
    for (int p = tid; p < 8 * K; p += 256) {
        int q = p / K, k = p - q * K;
        const float* wv = wlo + q * 64;
        const float* xr = &xoL[k * 68];
        float acc = 0.f;
        #pragma unroll
        for (int c0 = 0; c0 < 64; c0 += 4) {
            float4 xv = *(const float4*)&xr[c0];
            float4 w4 = *(const float4*)&wv[c0];
            acc += xv.x * w4.x + xv.y * w4.y + xv.z * w4.z + xv.w * w4.w;
        }
        sco[(size_t)g * 8 * K + p] = acc;
    }
}

// ---------------------------------------------------------------------------
// Fused GAT0 + low-rank fuse, temporal. Rank-1 factored softmax (no exp in
// hot paths). Block = (g,h) XCD-swizzled, 256 threads, 4x4 register tile.
// ---------------------------------------------------------------------------
__global__ __launch_bounds__(256, 8) void gatfuse_t(
    const float* __restrict__ sc0,  // (1600,8,64)
    const float* __restrict__ sc1,  // (1600,8,32)
    const float* __restrict__ sc2,  // (1600,8,12)
    const float* __restrict__ L1,   // (4,64,32)
    const float* __restrict__ R1,   // (4,32,64)
    const float* __restrict__ L2,   // (4,64,12)
    const float* __restrict__ R2,   // (4,12,64)
    float* __restrict__ out)        // (1600,4,64,64)
{
    const int bid = blockIdx.x;
    const int g = (bid & 7) | ((bid >> 5) << 3);
    const int h = (bid >> 3) & 3;
    const int tid = threadIdx.x;
    __shared__ float t1T[32 * 64];   // [l][j]
    __shared__ float t2T[12 * 64];   // [l][j]
    __shared__ float A1[32 * 36];    // [k][l]
    __shared__ float A2[12 * 13];    // [k][l]
    __shared__ float4 row0[64], col0[64], row1[32], col1[32], row2[12], col2[12];
    __shared__ float mxs[3];

    // ---- stage raw scores into .x
    if (tid < 64) col0[tid].x = sc0[((size_t)g * 8 + h) * 64 + tid];
    else if (tid < 128) row0[tid - 64].x = sc0[((size_t)g * 8 + 4 + h) * 64 + (tid - 64)];
    else if (tid < 160) col1[tid - 128].x = sc1[((size_t)g * 8 + h) * 32 + (tid - 128)];
    else if (tid < 192) row1[tid - 160].x = sc1[((size_t)g * 8 + 4 + h) * 32 + (tid - 160)];
    else if (tid < 204) col2[tid - 192].x = sc2[((size_t)g * 8 + h) * 12 + (tid - 192)];
    else if (tid < 216) row2[tid - 204].x = sc2[((size_t)g * 8 + 4 + h) * 12 + (tid - 204)];
    __syncthreads();

    // ---- rows: (a2, exp(a2-mx), exp(0.2(a2-mx)))
    if (tid < 64) {
        float mx = row0[0].x;
        for (int i = 1; i < 64; ++i) mx = fmaxf(mx, row0[i].x);
        if (tid == 0) mxs[0] = mx;
        float a = row0[tid].x;
        row0[tid] = make_float4(a, __expf(a - mx), __expf(0.2f * (a - mx)), 0.f);
    } else if (tid < 96) {
        float mx = row1[0].x;
        for (int k = 1; k < 32; ++k) mx = fmaxf(mx, row1[k].x);
        if (tid == 64) mxs[1] = mx;
        int k = tid - 64;
        float a = row1[k].x;
        row1[k] = make_float4(a, __expf(a - mx), __expf(0.2f * (a - mx)), 0.f);
    } else if (tid < 108) {
        float mx = row2[0].x;
        for (int k = 1; k < 12; ++k) mx = fmaxf(mx, row2[k].x);
        if (tid == 96) mxs[2] = mx;
        int k = tid - 96;
        float a = row2[k].x;
        row2[k] = make_float4(a, __expf(a - mx), __expf(0.2f * (a - mx)), 0.f);
    }
    __syncthreads();

    // ---- cols: (a1, em, fm) with em=Em*iv, fm=Fm*iv (masked sums of ei/fi)
    if (tid < 64) {
        float a = col0[tid].x, mx = mxs[0];
        float mj = leaky(a + mx);
        float Em = __expf(a + mx - mj);
        float Fm = __expf(0.2f * (a + mx) - mj);
        float S1 = 0.f, S2 = 0.f;
        for (int i = 0; i < 64; ++i) {
            float4 r = row0[i];
            bool c = (a + r.x >= 0.f);
            S1 += c ? r.y : 0.f;
            S2 += c ? 0.f : r.z;
        }
        float iv = 1.f / (Em * S1 + Fm * S2);
        col0[tid] = make_float4(a, Em * iv, Fm * iv, 0.f);
    } else if (tid < 96) {
        int l = tid - 64;
        float a = col1[l].x, mx = mxs[1];
        float mj = leaky(a + mx);
        float E = __expf(a + mx - mj);
        float F = __expf(0.2f * (a + mx) - mj);
        float S1 = 0.f, S2 = 0.f;
        for (int k = 0; k < 32; ++k) {
            float4 r = row1[k];
            bool c = (a + r.x >= 0.f);
            S1 += c ? r.y : 0.f;
            S2 += c ? 0.f : r.z;
        }
        float iv = 1.f / (E * S1 + F * S2);
        col1[l] = make_float4(a, E * iv, F * iv, 0.f);
    } else if (tid < 108) {
        int l = tid - 96;
        float a = col2[l].x, mx = mxs[2];
        float mj = leaky(a + mx);
        float E = __expf(a + mx - mj);
        float F = __expf(0.2f * (a + mx) - mj);
        float S1 = 0.f, S2 = 0.f;
        for (int k = 0; k < 12; ++k) {
            float4 r = row2[k];
            bool c = (a + r.x >= 0.f);
            S1 += c ? r.y : 0.f;
            S2 += c ? 0.f : r.z;
        }
        float iv = 1.f / (E * S1 + F * S2);
        col2[l] = make_float4(a, E * iv, F * iv, 0.f);
    }
    __syncthreads();

    // ---- build A1 (32x32), A2 (12x12): rank-1 masked products, no exp
    #pragma unroll
    for (int q = 0; q < 4; ++q) {
        int idx = q * 256 + tid;
        int k = idx >> 5, l = idx & 31;
        float4 rk = row1[k];
        float4 cl = col1[l];
        A1[k * 36 + l] = (cl.x + rk.x >= 0.f) ? cl.y * rk.y : cl.z * rk.z;
    }
    if (tid < 144) {
        int k = tid / 12, l = tid - k * 12;
        float4 rk = row2[k];
        float4 cl = col2[l];
        A2[k * 13 + l] = (cl.x + rk.x >= 0.f) ? cl.y * rk.y : cl.z * rk.z;
    }
    __syncthreads();

    // ---- t1T[l][j] = sum_k L1[j][k]*A1[k][l]
    {
        const int j = tid & 63, l0 = (tid >> 6) * 8;
        const float* ljrow = L1 + ((size_t)h * 64 + j) * 32;
        float acc8[8] = {};
        for (int k = 0; k < 32; ++k) {
            float lk = ljrow[k];
            float4 a4a = *(const float4*)&A1[k * 36 + l0];
            float4 a4b = *(const float4*)&A1[k * 36 + l0 + 4];
            acc8[0] += lk * a4a.x; acc8[1] += lk * a4a.y;
            acc8[2] += lk * a4a.z; acc8[3] += lk * a4a.w;
            acc8[4] += lk * a4b.x; acc8[5] += lk * a4b.y;
            acc8[6] += lk * a4b.z; acc8[7] += lk * a4b.w;
        }
        #pragma unroll
        for (int lo = 0; lo < 8; ++lo) t1T[(l0 + lo) * 64 + j] = acc8[lo];
        // t2T: 3 l's per thread
        const int lb = (tid >> 6) * 3;
        float lj2[12];
        const float4* lp2 = (const float4*)(L2 + ((size_t)h * 64 + j) * 12);
        #pragma unroll
        for (int q = 0; q < 3; ++q) {
            float4 v = lp2[q];
            lj2[q * 4] = v.x; lj2[q * 4 + 1] = v.y;
            lj2[q * 4 + 2] = v.z; lj2[q * 4 + 3] = v.w;
        }
        #pragma unroll
        for (int lo = 0; lo < 3; ++lo) {
            int l = lb + lo;
            float acc = 0.f;
            #pragma unroll
            for (int k = 0; k < 12; ++k) acc += lj2[k] * A2[k * 13 + l];
            t2T[l * 64 + j] = acc;
        }
    }
    __syncthreads();

    // ---- main 4x4 register-tiled output
    const int i0 = (tid >> 4) << 2, m0 = (tid & 15) << 2;
    float acc[4][4];
    {
        float4 cm[4] = {col0[m0], col0[m0 + 1], col0[m0 + 2], col0[m0 + 3]};
        float4 ri[4] = {row0[i0], row0[i0 + 1], row0[i0 + 2], row0[i0 + 3]};
        #pragma unroll
        for (int r = 0; r < 4; ++r)
            #pragma unroll
            for (int c = 0; c < 4; ++c)
                acc[r][c] = (cm[c].x + ri[r].x >= 0.f) ? cm[c].y * ri[r].y
                                                       : cm[c].z * ri[r].z;
    }
    const float* r1b = R1 + (size_t)h * 2048;
    #pragma unroll 8
    for (int l = 0; l < 32; ++l) {
        float4 t4 = *(const float4*)&t1T[l * 64 + i0];
        float4 r4 = *(const float4*)(r1b + l * 64 + m0);
        float tv[4] = {t4.x, t4.y, t4.z, t4.w};
        float rv[4] = {r4.x, r4.y, r4.z, r4.w};
        #pragma unroll
        for (int r = 0; r < 4; ++r)
            #pragma unroll
            for (int c = 0; c < 4; ++c) acc[r][c] += tv[r] * rv[c];
    }
    const float* r2b = R2 + (size_t)h * 768;
    #pragma unroll 4
    for (int l = 0; l < 12; ++l) {
        float4 t4 = *(const float4*)&t2T[l * 64 + i0];
        float4 r4 = *(const float4*)(r2b + l * 64 + m0);
        float tv[4] = {t4.x, t4.y, t4.z, t4.w};
        float rv[4] = {r4.x, r4.y, r4.z, r4.w};
        #pragma unroll
        for (int r = 0; r < 4; ++r)
            #pragma unroll
            for (int c = 0; c < 4; ++c) acc[r][c] += tv[r] * rv[c];
    }
    float* op = out + ((size_t)g * 4 + h) * 4096;
    #pragma unroll
    for (int r = 0; r < 4; ++r)
        *(float4*)&op[(i0 + r) * 64 + m0] =
            make_float4(acc[r][0], acc[r][1], acc[r][2], acc[r][3]);
}

// ---------------------------------------------------------------------------
// Fused GAT0 + fuse, spatial, rank-1 factored softmax. Block = g, head = tid>>6.
// ---------------------------------------------------------------------------
__global__ __launch_bounds__(256, 5) void gatfuse_s(
    const float* __restrict__ sc0,  // (4096,8,25)
    const float* __restrict__ sc1,  // (4096,8,12)
    const float* __restrict__ sc2,  // (4096,8,5)
    const float* __restrict__ L1,   // (4,25,12)
    const float* __restrict__ R1,   // (4,12,25)
    const float* __restrict__ L2,   // (4,25,5)
    const float* __restrict__ R2,   // (4,5,25)
    float* __restrict__ out)        // (4096,4,25,25)
{
    const int g = blockIdx.x;
    const int tid = threadIdx.x;
    const int h = tid >> 6, t = tid & 63;
    __shared__ float4 row0[4][25], col0[4][25];
    __shared__ float4 row1[4][12], col1[4][12];
    __shared__ float4 row2[4][5], col2[4][5];
    __shared__ float A1[4][12 * 13];   // [k][l]
    __shared__ float A2[4][5 * 6];     // [k][l]
    __shared__ float t1l[4][25 * 16];  // [i][l] pad zero
    __shared__ float t2l[4][25 * 8];   // [i][l] pad zero
    __shared__ float r1T[4][25 * 16];  // [m][l] pad zero
    __shared__ float r2T[4][25 * 8];   // [m][l] pad zero
    __shared__ float mxs[4][3];

    // ---- stage raw scores (.x) + R tiles
    for (int p = t; p < 84; p += 64) {
        if (p < 25)      col0[h][p].x      = sc0[((size_t)g * 8 + h) * 25 + p];
        else if (p < 50) row0[h][p - 25].x = sc0[((size_t)g * 8 + 4 + h) * 25 + (p - 25)];
        else if (p < 62) col1[h][p - 50].x = sc1[((size_t)g * 8 + h) * 12 + (p - 50)];
        else if (p < 74) row1[h][p - 62].x = sc1[((size_t)g * 8 + 4 + h) * 12 + (p - 62)];
        else if (p < 79) col2[h][p - 74].x = sc2[((size_t)g * 8 + h) * 5 + (p - 74)];
        else             row2[h][p - 79].x = sc2[((size_t)g * 8 + 4 + h) * 5 + (p - 79)];
    }
    for (int idx = t; idx < 400; idx += 64) {
        int m = idx >> 4, l = idx & 15;
        r1T[h][idx] = (l < 12) ? R1[h * 300 + l * 25 + m] : 0.f;
    }
    for (int idx = t; idx < 200; idx += 64) {
        int m = idx >> 3, l = idx & 7;
        r2T[h][idx] = (l < 5) ? R2[h * 125 + l * 25 + m] : 0.f;
    }
    __syncthreads();

    // ---- rows
    if (t < 25) {
        float mx = row0[h][0].x;
        for (int i = 1; i < 25; ++i) mx = fmaxf(mx, row0[h][i].x);
        if (t == 0) mxs[h][0] = mx;
        float a = row0[h][t].x;
        row0[h][t] = make_float4(a, __expf(a - mx), __expf(0.2f * (a - mx)), 0.f);
    } else if (t >= 32 && t < 44) {
        float mx = row1[h][0].x;
        for (int k = 1; k < 12; ++k) mx = fmaxf(mx, row1[h][k].x);
        if (t == 32) mxs[h][1] = mx;
        int k = t - 32;
        float a = row1[h][k].x;
        row1[h][k] = make_float4(a, __expf(a - mx), __expf(0.2f * (a - mx)), 0.f);
    } else if (t >= 48 && t < 53) {
        float mx = row2[h][0].x;
        for (int k = 1; k < 5; ++k) mx = fmaxf(mx, row2[h][k].x);
        if (t == 48) mxs[h][2] = mx;
        int k = t - 48;
        float a = row2[h][k].x;
        row2[h][k] = make_float4(a, __expf(a - mx), __expf(0.2f * (a - mx)), 0.f);
    }
    __syncthreads();

    // ---- cols
    if (t < 25) {
        float a = col0[h][t].x, mx = mxs[h][0];
        float mj = leaky(a + mx);
        float E = __expf(a + mx - mj);
        float F = __expf(0.2f * (a + mx) - mj);
        float S1 = 0.f, S2 = 0.f;
        for (int i = 0; i < 25; ++i) {
            float4 r = row0[h][i];
            bool c = (a + r.x >= 0.f);
            S1 += c ? r.y : 0.f;
            S2 += c ? 0.f : r.z;
        }
        float iv = 1.f / (E * S1 + F * S2);
        col0[h][t] = make_float4(a, E * iv, F * iv, 0.f);
    } else if (t >= 32 && t < 44) {
        int l = t - 32;
        float a = col1[h][l].x, mx = mxs[h][1];
        float mj = leaky(a + mx);
        float E = __expf(a + mx - mj);
        float F = __expf(0.2f * (a + mx) - mj);
        float S1 = 0.f, S2 = 0.f;
        for (int k = 0; k < 12; ++k) {
            float4 r = row1[h][k];
            bool c = (a + r.x >= 0.f);
            S1 += c ? r.y : 0.f;
            S2 += c ? 0.f : r.z;
        }
        float iv = 1.f / (E * S1 + F * S2);
        col1[h][l] = make_float4(a, E * iv, F * iv, 0.f);
    } else if (t >= 48 && t < 53) {
        int l = t - 48;
        float a = col2[h][l].x, mx = mxs[h][2];
        float mj = leaky(a + mx);
        float E = __expf(a + mx - mj);
        float F = __expf(0.2f * (a + mx) - mj);
        float S1 = 0.f, S2 = 0.f;
        for (int k = 0; k < 5; ++k) {
            float4 r = row2[h][k];
            bool c = (a + r.x >= 0.f);
            S1 += c ? r.y : 0.f;
            S2 += c ? 0.f : r.z;
        }
        float iv = 1.f / (E * S1 + F * S2);
        col2[h][l] = make_float4(a, E * iv, F * iv, 0.f);
    }
    __syncthreads();

    // ---- build A1 (12x12), A2 (5x5)
    for (int p = t; p < 144; p += 64) {
        int k = p / 12, l = p - k * 12;
        float4 rk = row1[h][k];
        float4 cl = col1[h][l];
        A1[h][k * 13 + l] = (cl.x + rk.x >= 0.f) ? cl.y * rk.y : cl.z * rk.z;
    }
    if (t < 25) {
        int k = t / 5, l = t - (t / 5) * 5;
        float4 rk = row2[h][k];
        float4 cl = col2[h][l];
        A2[h][k * 6 + l] = (cl.x + rk.x >= 0.f) ? cl.y * rk.y : cl.z * rk.z;
    }
    __syncthreads();

    // ---- t1l[i][l] = sum_k L1[i][k] A1[k][l] (zero-padded)
    if (t < 25) {
        float lj[12];
        const float4* lp = (const float4*)(L1 + ((size_t)h * 25 + t) * 12);
        #pragma unroll
        for (int q = 0; q < 3; ++q) {
            float4 v = lp[q];
            lj[q * 4] = v.x; lj[q * 4 + 1] = v.y; lj[q * 4 + 2] = v.z; lj[q * 4 + 3] = v.w;
        }
        #pragma unroll
        for (int l = 0; l < 12; ++l) {
            float acc = 0.f;
            #pragma unroll
            for (int k = 0; k < 12; ++k) acc += lj[k] * A1[h][k * 13 + l];
            t1l[h][t * 16 + l] = acc;
        }
        #pragma unroll
        for (int l = 12; l < 16; ++l) t1l[h][t * 16 + l] = 0.f;
        float lj2[5];
        const float* lp2 = L2 + ((size_t)h * 25 + t) * 5;
        #pragma unroll
        for (int k = 0; k < 5; ++k) lj2[k] = lp2[k];
        #pragma unroll
        for (int l = 0; l < 5; ++l) {
            float acc = 0.f;
            #pragma unroll
            for (int k = 0; k < 5; ++k) acc += lj2[k] * A2[h][k * 6 + l];
            t2l[h][t * 8 + l] = acc;
        }
        #pragma unroll
        for (int l = 5; l < 8; ++l) t2l[h][t * 8 + l] = 0.f;
    }
    __syncthreads();

    // ---- output: 625 per head
    float* op = out + ((size_t)g * 4 + h) * 625;
    for (int idx = t; idx < 625; idx += 64) {
        int i = idx / 25, m = idx - i * 25;
        float4 cm = col0[h][m];
        float4 ri = row0[h][i];
        float val = (cm.x + ri.x >= 0.f) ? cm.y * ri.y : cm.z * ri.z;
        const float* t1r = &t1l[h][i * 16];
        const float* r1c = &r1T[h][m * 16];
        #pragma unroll
        for (int q = 0; q < 4; ++q) {
            float4 tv = *(const float4*)&t1r[q * 4];
            float4 rv = *(const float4*)&r1c[q * 4];
            val += tv.x * rv.x + tv.y * rv.y + tv.z * rv.z + tv.w * rv.w;
        }
        const float* t2r = &t2l[h][i * 8];
        const float* r2c = &r2T[h][m * 8];
        #pragma unroll
        for (int q = 0; q < 2; ++q) {
            float4 tv = *(const float4*)&t2r[q * 4];
            float4 rv = *(const float4*)&r2c[q * 4];
            val += tv.x * rv.x + tv.y * rv.y + tv.z * rv.z + tv.w * rv.w;
        }
        op[idx] = val;
    }
}

// ---------------------------------------------------------------------------
extern "C" void kernel_launch(void* const* d_in, const int* in_sizes, int n_in,
                              void* d_out, int out_size, void* d_ws, size_t ws_size,
                              hipStream_t stream) {
    const float* src    = (const float*)d_in[0];
    const float* lin    = (const float*)d_in[1];
    const float* asrc   = (const float*)d_in[2];
    const float* adst   = (const float*)d_in[3];
    const float* sp0_W1 = (const float*)d_in[4];
    const float* sp0_b1 = (const float*)d_in[5];
    const float* sp0_W2 = (const float*)d_in[6];
    const float* sp0_b2 = (const float*)d_in[7];
    const float* sp1_W1 = (const float*)d_in[8];
    const float* sp1_b1 = (const float*)d_in[9];
    const float* sp1_W2 = (const float*)d_in[10];
    const float* sp1_b2 = (const float*)d_in[11];
    const float* tp0_W1 = (const float*)d_in[12];
    const float* tp0_b1 = (const float*)d_in[13];
    const float* tp0_W2 = (const float*)d_in[14];
    const float* tp0_b2 = (const float*)d_in[15];
    const float* tp1_W1 = (const float*)d_in[16];
    const float* tp1_b1 = (const float*)d_in[17];
    const float* tp1_W2 = (const float*)d_in[18];
    const float* tp1_b2 = (const float*)d_in[19];
    const float* sl0    = (const float*)d_in[20];
    const float* sr0    = (const float*)d_in[21];
    const float* sl1    = (const float*)d_in[22];
    const float* sr1    = (const float*)d_in[23];
    const float* tl0    = (const float*)d_in[24];
    const float* tr0    = (const float*)d_in[25];
    const float* tl1    = (const float*)d_in[26];
    const float* tr1    = (const float*)d_in[27];

    float* out_s = (float*)d_out;                 // (4096,4,25,25)
    float* out_t = out_s + 10240000;              // (1600,4,64,64)

    float* ws   = (float*)d_ws;
    float* wbuf = ws;                             // 3072 used (reserve 4096)
    float* wT   = ws + 4096;                      // 20480

    float* sp0_W1T = wT;
    float* sp1_W1T = wT + 4096;
    float* tp0_W1T = wT + 8192;
    float* tp1_W1T = wT + 12288;
    float* sp0_W2T = wT + 16384;                  // 64x12
    float* sp1_W2T = wT + 17152;                  // 64x8
    float* tp0_W2T = wT + 17664;                  // 64x32
    float* tp1_W2T = wT + 19712;                  // 64x12

    float* a = ws + 24576;
    float* xs1  = a;              a += 3145728;   // 4096*12*64
    float* xt1  = a;              a += 3276800;   // 1600*32*64
    float* scS0 = a;              a += 819200;    // 4096*8*25
    float* scS1 = a;              a += 393216;    // 4096*8*12
    float* scS2 = a;              a += 163840;    // 4096*8*5
    float* scT0 = a;              a += 819200;    // 1600*8*64
    float* scT1 = a;              a += 409600;    // 1600*8*32
    float* scT2 = a;              a += 153600;    // 1600*8*12

    wprep_kernel<<<6, 256, 0, stream>>>(lin, asrc, adst, wbuf);
    wtrans_kernel<<<80, 256, 0, stream>>>(sp0_W1, sp1_W1, tp0_W1, tp1_W1,
                                          sp0_W2, sp1_W2, tp0_W2, tp1_W2, wT);

    // ---- spatial branch ----
    pool_kernel<25, 12, 12, 1, 1><<<4096, 256, 0, stream>>>(
        src, sp0_W1T, sp0_b1, sp0_W2T, sp0_b2,
        wbuf + 0 * 512, wbuf + 1 * 512, xs1, scS0, scS1);
    pool_kernel<12, 5, 8, 0, 0><<<4096, 256, 0, stream>>>(
        xs1, sp1_W1T, sp1_b1, sp1_W2T, sp1_b2,
        nullptr, wbuf + 2 * 512, nullptr, nullptr, scS2);
    gatfuse_s<<<4096, 256, 0, stream>>>(scS0, scS1, scS2, sl0, sr0, sl1, sr1, out_s);

    // ---- temporal branch ----
    pool_kernel<64, 32, 32, 2, 1><<<1600, 256, 0, stream>>>(
        src, tp0_W1T, tp0_b1, tp0_W2T, tp0_b2,
        wbuf + 3 * 512, wbuf + 4 * 512, xt1, scT0, scT1);
    pool_kernel<32, 12, 12, 0, 0><<<1600, 256, 0, stream>>>(
        xt1, tp1_W1T, tp1_b1, tp1_W2T, tp1_b2,
        nullptr, wbuf + 5 * 512, nullptr, nullptr, scT2);
    gatfuse_t<<<6400, 256, 0, stream>>>(scT0, scT1, scT2, tl0, tr0, tl1, tr1, out_t);
}